// Round 1
// baseline (2697.969 us; speedup 1.0000x reference)
//
#include <hip/hip_runtime.h>
#include <hip/hip_bf16.h>

#define NB   65536
#define KD   10
#define NG   20
#define NH   200     // KD*NG
#define NH1  400
#define NIN  784

__device__ inline float bf2f(unsigned short u) {
  union { unsigned int i; float f; } x; x.i = ((unsigned int)u) << 16; return x.f;
}

// C[m][n] = act( sum_k A[m][k]*W[n][k] + bias[n] ), fp64 accumulate (quantization path).
// BM=BN=64, BK=16, 256 threads, 4x4 micro-tile per thread.
template<int ACT>
__global__ __launch_bounds__(256) void gemm_nt_f64(
    const float* __restrict__ A, const float* __restrict__ W,
    const float* __restrict__ bias, float* __restrict__ C,
    int M, int N, int K)
{
  __shared__ double As[16][65];
  __shared__ double Bs[16][65];
  const int tid = threadIdx.x;
  const int tx = tid & 15, ty = tid >> 4;
  const int m0 = blockIdx.x * 64;
  const int n0 = blockIdx.y * 64;
  const int lr = tid >> 2;          // 0..63 : tile row for loads
  const int lk = (tid & 3) * 4;     // 0,4,8,12 : k offset for float4 load
  double acc[4][4];
  #pragma unroll
  for (int i = 0; i < 4; ++i)
    #pragma unroll
    for (int j = 0; j < 4; ++j) acc[i][j] = 0.0;

  for (int k0 = 0; k0 < K; k0 += 16) {
    float4 va = *reinterpret_cast<const float4*>(A + (size_t)(m0 + lr) * K + k0 + lk);
    float4 vb = make_float4(0.f, 0.f, 0.f, 0.f);
    if (n0 + lr < N)
      vb = *reinterpret_cast<const float4*>(W + (size_t)(n0 + lr) * K + k0 + lk);
    As[lk + 0][lr] = (double)va.x; As[lk + 1][lr] = (double)va.y;
    As[lk + 2][lr] = (double)va.z; As[lk + 3][lr] = (double)va.w;
    Bs[lk + 0][lr] = (double)vb.x; Bs[lk + 1][lr] = (double)vb.y;
    Bs[lk + 2][lr] = (double)vb.z; Bs[lk + 3][lr] = (double)vb.w;
    __syncthreads();
    #pragma unroll
    for (int kk = 0; kk < 16; ++kk) {
      double a[4], b[4];
      #pragma unroll
      for (int i = 0; i < 4; ++i) a[i] = As[kk][ty + 16 * i];
      #pragma unroll
      for (int j = 0; j < 4; ++j) b[j] = Bs[kk][tx + 16 * j];
      #pragma unroll
      for (int i = 0; i < 4; ++i)
        #pragma unroll
        for (int j = 0; j < 4; ++j)
          acc[i][j] = fma(a[i], b[j], acc[i][j]);
    }
    __syncthreads();
  }
  #pragma unroll
  for (int i = 0; i < 4; ++i) {
    const int m = m0 + ty + 16 * i;
    #pragma unroll
    for (int j = 0; j < 4; ++j) {
      const int n = n0 + tx + 16 * j;
      if (n < N) {
        float r = (float)(acc[i][j] + (double)bias[n]);
        if (ACT) r = fmaxf(r, 0.f);
        C[(size_t)m * N + n] = r;
      }
    }
  }
}

// recon = tanh( h3(bf16) @ W4^T + b4 ), fp32 accumulate.
__global__ __launch_bounds__(256) void gemm_nt_bf16a_tanh(
    const __hip_bfloat16* __restrict__ A, const float* __restrict__ W,
    const float* __restrict__ bias, float* __restrict__ C,
    int M, int N, int K)
{
  __shared__ float As[16][65];
  __shared__ float Bs[16][65];
  const int tid = threadIdx.x;
  const int tx = tid & 15, ty = tid >> 4;
  const int m0 = blockIdx.x * 64;
  const int n0 = blockIdx.y * 64;
  const int lr = tid >> 2;
  const int lk = (tid & 3) * 4;
  const unsigned short* Au = reinterpret_cast<const unsigned short*>(A);
  float acc[4][4];
  #pragma unroll
  for (int i = 0; i < 4; ++i)
    #pragma unroll
    for (int j = 0; j < 4; ++j) acc[i][j] = 0.f;

  for (int k0 = 0; k0 < K; k0 += 16) {
    ushort4 va = *reinterpret_cast<const ushort4*>(Au + (size_t)(m0 + lr) * K + k0 + lk);
    float4 vb = make_float4(0.f, 0.f, 0.f, 0.f);
    if (n0 + lr < N)
      vb = *reinterpret_cast<const float4*>(W + (size_t)(n0 + lr) * K + k0 + lk);
    As[lk + 0][lr] = bf2f(va.x); As[lk + 1][lr] = bf2f(va.y);
    As[lk + 2][lr] = bf2f(va.z); As[lk + 3][lr] = bf2f(va.w);
    Bs[lk + 0][lr] = vb.x; Bs[lk + 1][lr] = vb.y;
    Bs[lk + 2][lr] = vb.z; Bs[lk + 3][lr] = vb.w;
    __syncthreads();
    #pragma unroll
    for (int kk = 0; kk < 16; ++kk) {
      float a[4], b[4];
      #pragma unroll
      for (int i = 0; i < 4; ++i) a[i] = As[kk][ty + 16 * i];
      #pragma unroll
      for (int j = 0; j < 4; ++j) b[j] = Bs[kk][tx + 16 * j];
      #pragma unroll
      for (int i = 0; i < 4; ++i)
        #pragma unroll
        for (int j = 0; j < 4; ++j)
          acc[i][j] = fmaf(a[i], b[j], acc[i][j]);
    }
    __syncthreads();
  }
  #pragma unroll
  for (int i = 0; i < 4; ++i) {
    const int m = m0 + ty + 16 * i;
    #pragma unroll
    for (int j = 0; j < 4; ++j) {
      const int n = n0 + tx + 16 * j;
      if (n < N) {
        C[(size_t)m * N + n] = tanhf(acc[i][j] + bias[n]);
      }
    }
  }
}

// Nearest-codeword quantization in fp64: t_j = 0.5|c_j|^2 - v.c_j (same argmin as |v-c_j|^2).
__global__ __launch_bounds__(256) void quant_kernel(
    const float* __restrict__ z_e, const float* __restrict__ cb,
    float* __restrict__ emb, unsigned char* __restrict__ idx_out)
{
  __shared__ double cs[KD][KD];
  __shared__ double chalf[KD];
  const int tid = threadIdx.x;
  if (tid < KD * KD) cs[tid / KD][tid % KD] = (double)cb[tid];
  __syncthreads();
  if (tid < KD) {
    double s = 0.0;
    #pragma unroll
    for (int k = 0; k < KD; ++k) s += cs[tid][k] * cs[tid][k];
    chalf[tid] = 0.5 * s;
  }
  __syncthreads();

  const int gi = blockIdx.x * 256 + tid;     // group index, grid covers NB*NG exactly
  const int b = gi / NG;
  const int g = gi % NG;
  const float* zp = z_e + (size_t)b * NH + g;
  double v[KD];
  #pragma unroll
  for (int k = 0; k < KD; ++k) v[k] = (double)zp[k * NG];

  int best = 0; double bt = 1e300;
  #pragma unroll
  for (int j = 0; j < KD; ++j) {
    double t = chalf[j];
    #pragma unroll
    for (int k = 0; k < KD; ++k) t -= v[k] * cs[j][k];
    if (t < bt) { bt = t; best = j; }     // strict <  => first index wins ties (argmin semantics)
  }
  float* ep = emb + (size_t)b * NH + g;
  #pragma unroll
  for (int k = 0; k < KD; ++k) ep[k * NG] = (float)cs[best][k];
  idx_out[gi] = (unsigned char)best;
}

// P[g][c][j] = sum_k cb[c][k] * W3[j][k*NG + g]   (z_q @ W3^T collapses to table lookups)
__global__ __launch_bounds__(256) void build_table(
    const float* __restrict__ cb, const float* __restrict__ W3,
    float* __restrict__ P)
{
  const int i = blockIdx.x * 256 + threadIdx.x;
  if (i >= NG * KD * NH1) return;
  const int j = i % NH1;
  const int c = (i / NH1) % KD;
  const int g = i / (NH1 * KD);
  float s = 0.f;
  #pragma unroll
  for (int k = 0; k < KD; ++k)
    s = fmaf(cb[c * KD + k], W3[(size_t)j * NH + k * NG + g], s);
  P[i] = s;
}

// h3[b][j] = relu(b3[j] + sum_g P[g][idx[b,g]][j])  -> bf16
__global__ __launch_bounds__(256) void compute_h3(
    const unsigned char* __restrict__ idx, const float* __restrict__ P,
    const float* __restrict__ b3, __hip_bfloat16* __restrict__ h3)
{
  __shared__ unsigned char sidx[64][NG];
  const int tid = threadIdx.x;
  const int b0 = blockIdx.x * 64;
  for (int t = tid; t < 64 * NG; t += 256)
    sidx[t / NG][t % NG] = idx[(size_t)b0 * NG + t];
  __syncthreads();
  for (int s = 0; s < 64; ++s) {
    for (int j = tid; j < NH1; j += 256) {
      float acc = b3[j];
      #pragma unroll
      for (int g = 0; g < NG; ++g) {
        const int c = sidx[s][g];
        acc += P[(g * KD + c) * NH1 + j];
      }
      h3[(size_t)(b0 + s) * NH1 + j] = __float2bfloat16(fmaxf(acc, 0.f));
    }
  }
}

extern "C" void kernel_launch(void* const* d_in, const int* in_sizes, int n_in,
                              void* d_out, int out_size, void* d_ws, size_t ws_size,
                              hipStream_t stream) {
  const float* x  = (const float*)d_in[0];
  const float* W1 = (const float*)d_in[1];
  const float* b1 = (const float*)d_in[2];
  const float* W2 = (const float*)d_in[3];
  const float* b2 = (const float*)d_in[4];
  const float* W3 = (const float*)d_in[5];
  const float* b3 = (const float*)d_in[6];
  const float* W4 = (const float*)d_in[7];
  const float* b4 = (const float*)d_in[8];
  const float* cb = (const float*)d_in[9];

  float* out   = (float*)d_out;
  float* recon = out;                              // NB x 784
  float* z_e   = out + (size_t)NB * NIN;           // NB x 200
  float* emb   = z_e + (size_t)NB * NH;            // NB x 200

  char* ws = (char*)d_ws;
  float*          P   = (float*)ws;                           // 320 KB
  unsigned char*  idx = (unsigned char*)(ws + (1u << 20));    // 1.31 MB
  __hip_bfloat16* h3  = (__hip_bfloat16*)(ws + (4u << 20));   // 52.4 MB
  float* h1 = recon;   // reuse recon region (205 MB) as h1 scratch (105 MB); rewritten by GEMM4 last

  dim3 blk(256);
  // stage 1: h1 = relu(x @ W1^T + b1)    M=65536 N=400 K=784
  gemm_nt_f64<1><<<dim3(NB / 64, 7), blk, 0, stream>>>(x, W1, b1, h1, NB, NH1, NIN);
  // stage 2: z_e = h1 @ W2^T + b2        M=65536 N=200 K=400
  gemm_nt_f64<0><<<dim3(NB / 64, 4), blk, 0, stream>>>(h1, W2, b2, z_e, NB, NH, NH1);
  // stage 3a: codeword x W3 table
  build_table<<<(NG * KD * NH1 + 255) / 256, blk, 0, stream>>>(cb, W3, P);
  // stage 3b: quantize (exact argmin), write emb + indices
  quant_kernel<<<(NB * NG) / 256, blk, 0, stream>>>(z_e, cb, emb, idx);
  // stage 4: h3 = relu(b3 + sum_g P[g][idx]) -> bf16
  compute_h3<<<NB / 64, blk, 0, stream>>>(idx, P, b3, h3);
  // stage 5: recon = tanh(h3 @ W4^T + b4)  M=65536 N=784 K=400
  gemm_nt_bf16a_tanh<<<dim3(NB / 64, 13), blk, 0, stream>>>(h3, W4, b4, recon, NB, NIN, NH1);
}